// Round 10
// baseline (37.935 us; speedup 1.0000x reference)
//
#include <hip/hip_runtime.h>

// out[b,k] = sum_n exp(-2*pi*||dom_k - C[b,n]||^2)
// R10 = R9 structure + in-MFMA Schraudolph scale/bias (isolating R6's change).
//   B-side fragments are pre-scaled by 2^23 (exact bf16 exponent shift) and
//   the Schraudolph bias 126.9437 is folded into the dk slot, so the MFMA
//   emits d = 2^23*(e + 126.9437) directly. VALU tail per exp is 3 ops:
//   u = max(d,0); val = bitcast_f32((u32)u); acc += val.
//   (R6 failed with {this encoding + UNCLAMPED asm cvt}; R7 passed with
//    {unscaled encoding + clamped cvt}. This round: scaled + clamped.)
// K-slot map (A=atom, unscaled; B=dom, scaled by 2^23; dkf includes +126.9437):
//   lanes 0-31  (K0-7):  A={xh,yh,zh,wh,1,xl,yl,zl} B={pxh,pyh,pzh,1,dkh,pxh,pyh,pzh}*2^23
//   lanes 32-63 (K8-15): A={wl,1,xh,yh,zh,0,0,0}    B={1,dkl,pxl,pyl,pzl,0,0,0}*2^23
// Grid: 8 k-groups x 32 b = 256 blocks x 1024 thr (16 waves), 128 KB LDS,
// exclusive output ownership: no atomics, no memset.

#define NATOMS 4096
#define KTOT   2048
#define BLOCK  1024
#define ATILES 128    // 32-atom MFMA tiles (all atoms staged once)
#define TPW    64     // tiles per wave (half of ATILES)

typedef float  f32x16 __attribute__((ext_vector_type(16)));
typedef __bf16 bf16x8 __attribute__((ext_vector_type(8)));

__global__ __launch_bounds__(BLOCK) void theta_layer_kernel(
        const float* __restrict__ C, const float* __restrict__ dom,
        float* __restrict__ out) {
    constexpr float S2    = 9.064720283654388f;   // 2*pi / ln(2)
    constexpr float S1    = 18.129440567308776f;  // 4*pi / ln(2)
    constexpr float SCALE = 8388608.0f;           // 2^23
    constexpr float BIAS  = 126.9437f;            // Schraudolph bias

    __shared__ bf16x8 sA[ATILES * 64];  // 128 KB prepacked A-fragments

    const int tid  = threadIdx.x;
    const int lane = tid & 63;
    const int w    = tid >> 6;        // wave 0..15
    const int b    = blockIdx.y;
    const int kg   = blockIdx.x;      // k-group 0..7

    const __bf16 one = (__bf16)1.0f;
    const __bf16 zb  = (__bf16)0.0f;

    // ---- stage ALL of C[b] as A-fragments (4 atoms/thread), UNSCALED ----
    const float* Cb = C + (size_t)b * NATOMS * 3;
    for (int j = tid; j < NATOMS; j += BLOCK) {
        float x = Cb[3 * j + 0];
        float y = Cb[3 * j + 1];
        float z = Cb[3 * j + 2];
        __bf16 xh = (__bf16)x; __bf16 xl = (__bf16)(x - (float)xh);
        __bf16 yh = (__bf16)y; __bf16 yl = (__bf16)(y - (float)yh);
        __bf16 zh = (__bf16)z; __bf16 zl = (__bf16)(z - (float)zh);
        float wn = -S2 * (x * x + y * y + z * z);
        __bf16 wh = (__bf16)wn; __bf16 wl = (__bf16)(wn - (float)wh);
        const int t = j >> 5, r = j & 31;
        bf16x8 f0 = {xh, yh, zh, wh, one, xl, yl, zl};  // K0-7  (lanes 0-31)
        bf16x8 f1 = {wl, one, xh, yh, zh, zb, zb, zb};  // K8-15 (lanes 32-63)
        sA[t * 64 + r]      = f0;
        sA[t * 64 + 32 + r] = f1;
    }

    // ---- per-wave B fragment, SCALED by 2^23, bias folded into dk ----
    const int kt = kg * 8 + (w & 7);           // 0..63
    const int k  = kt * 32 + (lane & 31);
    const float dx = dom[3 * k + 0], dy = dom[3 * k + 1], dz = dom[3 * k + 2];
    const float px = S1 * dx, py = S1 * dy, pz = S1 * dz;
    __bf16 pxh = (__bf16)px; __bf16 pxl = (__bf16)(px - (float)pxh);
    __bf16 pyh = (__bf16)py; __bf16 pyl = (__bf16)(py - (float)pyh);
    __bf16 pzh = (__bf16)pz; __bf16 pzl = (__bf16)(pz - (float)pzh);
    const float dkf = -S2 * (dx * dx + dy * dy + dz * dz) + BIAS;
    __bf16 dkh = (__bf16)dkf; __bf16 dkl = (__bf16)(dkf - (float)dkh);

    // exact exponent shifts in bf16 (value*2^23)
    __bf16 pxh_s = (__bf16)((float)pxh * SCALE), pxl_s = (__bf16)((float)pxl * SCALE);
    __bf16 pyh_s = (__bf16)((float)pyh * SCALE), pyl_s = (__bf16)((float)pyl * SCALE);
    __bf16 pzh_s = (__bf16)((float)pzh * SCALE), pzl_s = (__bf16)((float)pzl * SCALE);
    __bf16 dkh_s = (__bf16)((float)dkh * SCALE), dkl_s = (__bf16)((float)dkl * SCALE);
    __bf16 s23   = (__bf16)SCALE;

    bf16x8 bfrag;
    if (lane < 32) {
        bf16x8 t0 = {pxh_s, pyh_s, pzh_s, s23, dkh_s, pxh_s, pyh_s, pzh_s};  // K0-7
        bfrag = t0;
    } else {
        bf16x8 t1 = {s23, dkl_s, pxl_s, pyl_s, pzl_s, zb, zb, zb};           // K8-15
        bfrag = t1;
    }

    __syncthreads();

    // ---- main loop: ds_read_b128 + mfma -> 16x (max + cvt + add) ----
    const f32x16 zero = {};
    float a0 = 0.f, a1 = 0.f, a2 = 0.f, a3 = 0.f;
    const int t0i = (w >> 3) * TPW;   // waves 0-7: tiles 0-63; 8-15: 64-127
    #pragma unroll 2
    for (int t = t0i; t < t0i + TPW; ++t) {
        bf16x8 af = sA[t * 64 + lane];
        f32x16 d = __builtin_amdgcn_mfma_f32_32x32x16_bf16(af, bfrag, zero, 0, 0, 0);
        #pragma unroll
        for (int i = 0; i < 4; ++i) {
            float u0 = fmaxf(d[i],      0.0f);
            float u1 = fmaxf(d[i + 4],  0.0f);
            float u2 = fmaxf(d[i + 8],  0.0f);
            float u3 = fmaxf(d[i + 12], 0.0f);
            a0 += __uint_as_float((unsigned)u0);
            a1 += __uint_as_float((unsigned)u1);
            a2 += __uint_as_float((unsigned)u2);
            a3 += __uint_as_float((unsigned)u3);
        }
    }
    float acc = (a0 + a1) + (a2 + a3);

    // ---- combine row-halves (lane ^ 32) ----
    float other = __shfl_xor(acc, 32, 64);
    float tot = acc + other;

    // ---- combine the two waves per k-tile via LDS (reuse sA), store ----
    __syncthreads();  // all reads of sA done
    float* red = (float*)sA;  // [16 waves][32 k]
    if (lane < 32) red[w * 32 + lane] = tot;
    __syncthreads();
    if (tid < 256) {
        const int t2 = tid >> 5;   // k-tile slot 0..7
        const int kc = tid & 31;
        float s = red[t2 * 32 + kc] + red[(t2 + 8) * 32 + kc];
        out[(size_t)b * KTOT + (kg * 8 + t2) * 32 + kc] = s;
    }
}

extern "C" void kernel_launch(void* const* d_in, const int* in_sizes, int n_in,
                              void* d_out, int out_size, void* d_ws, size_t ws_size,
                              hipStream_t stream) {
    const float* C   = (const float*)d_in[0];
    const float* dom = (const float*)d_in[1];
    float* out       = (float*)d_out;
    const int B = in_sizes[0] / (NATOMS * 3);  // 32
    dim3 grid(8, B);  // 8 k-groups x B, each block owns 256 k outputs
    theta_layer_kernel<<<grid, BLOCK, 0, stream>>>(C, dom, out);
}

// Round 12
// 34.425 us; speedup vs baseline: 1.1020x; 1.1020x over previous
//
#include <hip/hip_runtime.h>

// out[b,k] = sum_n exp(-2*pi*||dom_k - C[b,n]||^2)
// R12 = R11 + explicit pre-clamp before pknorm (R11 NaN'd: gfx950's
// v_cvt_pknorm_u16_f32 does NOT safely clamp negative inputs — same lesson
// as R6's v_cvt_u32_f32. fmaxf is the verified-safe clamp from R7/R9/R10).
//   MFMA emits f = 2^-9*(e + 126.9437) (split-bf16 encoding, B scaled 2^-9,
//   Schraudolph bias in dk slot; encoding validated by R10 at absmax 0.5).
//   Tail: c = max(f,0) x16; v_cvt_pknorm_u16_f32(c0,c1) -> two u16
//   = round(c*65535) ~= 2^7*(e+126.94) == bf16 bit pattern of exp2(e);
//   v_dot2_f32_bf16(acc, pair, {1,1}) accumulates both halves.
//   32 instr/tile vs R9's 64.
// K-slot map (A=atom, unscaled; B=dom, scaled by 2^-9; dk includes +126.9437):
//   lanes 0-31  (K0-7):  A={xh,yh,zh,wh,1,xl,yl,zl} B={pxh,pyh,pzh,1,dkh,pxh,pyh,pzh}*2^-9
//   lanes 32-63 (K8-15): A={wl,1,xh,yh,zh,0,0,0}    B={1,dkl,pxl,pyl,pzl,0,0,0}*2^-9
// Grid: 8 k-groups x 32 b = 256 blocks x 1024 thr (16 waves), 128 KB LDS,
// exclusive output ownership: no atomics, no memset.

#define NATOMS 4096
#define KTOT   2048
#define BLOCK  1024
#define ATILES 128    // 32-atom MFMA tiles (all atoms staged once)
#define TPW    64     // tiles per wave (half of ATILES)

typedef float  f32x16 __attribute__((ext_vector_type(16)));
typedef __bf16 bf16x8 __attribute__((ext_vector_type(8)));

__global__ __launch_bounds__(BLOCK) void theta_layer_kernel(
        const float* __restrict__ C, const float* __restrict__ dom,
        float* __restrict__ out) {
    constexpr float S2    = 9.064720283654388f;   // 2*pi / ln(2)
    constexpr float S1    = 18.129440567308776f;  // 4*pi / ln(2)
    constexpr float SCALE = 0.001953125f;         // 2^-9, exact in bf16
    constexpr float BIAS  = 126.9437f;            // Schraudolph bias

    __shared__ bf16x8 sA[ATILES * 64];  // 128 KB prepacked A-fragments

    const int tid  = threadIdx.x;
    const int lane = tid & 63;
    const int w    = tid >> 6;        // wave 0..15
    const int b    = blockIdx.y;
    const int kg   = blockIdx.x;      // k-group 0..7

    const __bf16 one = (__bf16)1.0f;
    const __bf16 zb  = (__bf16)0.0f;

    // ---- stage ALL of C[b] as A-fragments (4 atoms/thread), UNSCALED ----
    const float* Cb = C + (size_t)b * NATOMS * 3;
    for (int j = tid; j < NATOMS; j += BLOCK) {
        float x = Cb[3 * j + 0];
        float y = Cb[3 * j + 1];
        float z = Cb[3 * j + 2];
        __bf16 xh = (__bf16)x; __bf16 xl = (__bf16)(x - (float)xh);
        __bf16 yh = (__bf16)y; __bf16 yl = (__bf16)(y - (float)yh);
        __bf16 zh = (__bf16)z; __bf16 zl = (__bf16)(z - (float)zh);
        float wn = -S2 * (x * x + y * y + z * z);
        __bf16 wh = (__bf16)wn; __bf16 wl = (__bf16)(wn - (float)wh);
        const int t = j >> 5, r = j & 31;
        bf16x8 f0 = {xh, yh, zh, wh, one, xl, yl, zl};  // K0-7  (lanes 0-31)
        bf16x8 f1 = {wl, one, xh, yh, zh, zb, zb, zb};  // K8-15 (lanes 32-63)
        sA[t * 64 + r]      = f0;
        sA[t * 64 + 32 + r] = f1;
    }

    // ---- per-wave B fragment, SCALED by 2^-9, bias folded into dk ----
    const int kt = kg * 8 + (w & 7);           // 0..63
    const int k  = kt * 32 + (lane & 31);
    const float dx = dom[3 * k + 0], dy = dom[3 * k + 1], dz = dom[3 * k + 2];
    const float px = S1 * dx, py = S1 * dy, pz = S1 * dz;
    __bf16 pxh = (__bf16)px; __bf16 pxl = (__bf16)(px - (float)pxh);
    __bf16 pyh = (__bf16)py; __bf16 pyl = (__bf16)(py - (float)pyh);
    __bf16 pzh = (__bf16)pz; __bf16 pzl = (__bf16)(pz - (float)pzh);
    const float dkf = -S2 * (dx * dx + dy * dy + dz * dz) + BIAS;
    __bf16 dkh = (__bf16)dkf; __bf16 dkl = (__bf16)(dkf - (float)dkh);

    // exact exponent shifts in bf16 (value * 2^-9)
    __bf16 pxh_s = (__bf16)((float)pxh * SCALE), pxl_s = (__bf16)((float)pxl * SCALE);
    __bf16 pyh_s = (__bf16)((float)pyh * SCALE), pyl_s = (__bf16)((float)pyl * SCALE);
    __bf16 pzh_s = (__bf16)((float)pzh * SCALE), pzl_s = (__bf16)((float)pzl * SCALE);
    __bf16 dkh_s = (__bf16)((float)dkh * SCALE), dkl_s = (__bf16)((float)dkl * SCALE);
    __bf16 sc9   = (__bf16)SCALE;

    bf16x8 bfrag;
    if (lane < 32) {
        bf16x8 t0 = {pxh_s, pyh_s, pzh_s, sc9, dkh_s, pxh_s, pyh_s, pzh_s};  // K0-7
        bfrag = t0;
    } else {
        bf16x8 t1 = {sc9, dkl_s, pxl_s, pyl_s, pzl_s, zb, zb, zb};           // K8-15
        bfrag = t1;
    }

    __syncthreads();

    // ---- main loop: ds_read_b128 + mfma -> 16 max + 8 pknorm + 8 dot2 ----
    const f32x16 zero = {};
    float a0 = 0.f, a1 = 0.f, a2 = 0.f, a3 = 0.f;
    const unsigned ONES = 0x3F803F80u;  // {bf16 1.0, bf16 1.0}
    const int t0i = (w >> 3) * TPW;     // waves 0-7: tiles 0-63; 8-15: 64-127
    #pragma unroll 2
    for (int t = t0i; t < t0i + TPW; ++t) {
        bf16x8 af = sA[t * 64 + lane];
        f32x16 d = __builtin_amdgcn_mfma_f32_32x32x16_bf16(af, bfrag, zero, 0, 0, 0);
        float c0  = fmaxf(d[0],  0.0f), c1  = fmaxf(d[1],  0.0f);
        float c2  = fmaxf(d[2],  0.0f), c3  = fmaxf(d[3],  0.0f);
        float c4  = fmaxf(d[4],  0.0f), c5  = fmaxf(d[5],  0.0f);
        float c6  = fmaxf(d[6],  0.0f), c7  = fmaxf(d[7],  0.0f);
        float c8  = fmaxf(d[8],  0.0f), c9  = fmaxf(d[9],  0.0f);
        float c10 = fmaxf(d[10], 0.0f), c11 = fmaxf(d[11], 0.0f);
        float c12 = fmaxf(d[12], 0.0f), c13 = fmaxf(d[13], 0.0f);
        float c14 = fmaxf(d[14], 0.0f), c15 = fmaxf(d[15], 0.0f);
        unsigned p0, p1, p2, p3, p4, p5, p6, p7;
        asm("v_cvt_pknorm_u16_f32 %0, %1, %2" : "=v"(p0) : "v"(c0),  "v"(c1));
        asm("v_cvt_pknorm_u16_f32 %0, %1, %2" : "=v"(p1) : "v"(c2),  "v"(c3));
        asm("v_cvt_pknorm_u16_f32 %0, %1, %2" : "=v"(p2) : "v"(c4),  "v"(c5));
        asm("v_cvt_pknorm_u16_f32 %0, %1, %2" : "=v"(p3) : "v"(c6),  "v"(c7));
        asm("v_cvt_pknorm_u16_f32 %0, %1, %2" : "=v"(p4) : "v"(c8),  "v"(c9));
        asm("v_cvt_pknorm_u16_f32 %0, %1, %2" : "=v"(p5) : "v"(c10), "v"(c11));
        asm("v_cvt_pknorm_u16_f32 %0, %1, %2" : "=v"(p6) : "v"(c12), "v"(c13));
        asm("v_cvt_pknorm_u16_f32 %0, %1, %2" : "=v"(p7) : "v"(c14), "v"(c15));
        asm("v_dot2_f32_bf16 %0, %1, %2, %0" : "+v"(a0) : "v"(p0), "v"(ONES));
        asm("v_dot2_f32_bf16 %0, %1, %2, %0" : "+v"(a1) : "v"(p1), "v"(ONES));
        asm("v_dot2_f32_bf16 %0, %1, %2, %0" : "+v"(a2) : "v"(p2), "v"(ONES));
        asm("v_dot2_f32_bf16 %0, %1, %2, %0" : "+v"(a3) : "v"(p3), "v"(ONES));
        asm("v_dot2_f32_bf16 %0, %1, %2, %0" : "+v"(a0) : "v"(p4), "v"(ONES));
        asm("v_dot2_f32_bf16 %0, %1, %2, %0" : "+v"(a1) : "v"(p5), "v"(ONES));
        asm("v_dot2_f32_bf16 %0, %1, %2, %0" : "+v"(a2) : "v"(p6), "v"(ONES));
        asm("v_dot2_f32_bf16 %0, %1, %2, %0" : "+v"(a3) : "v"(p7), "v"(ONES));
    }
    float acc = (a0 + a1) + (a2 + a3);

    // ---- combine row-halves (lane ^ 32) ----
    float other = __shfl_xor(acc, 32, 64);
    float tot = acc + other;

    // ---- combine the two waves per k-tile via LDS (reuse sA), store ----
    __syncthreads();  // all reads of sA done
    float* red = (float*)sA;  // [16 waves][32 k]
    if (lane < 32) red[w * 32 + lane] = tot;
    __syncthreads();
    if (tid < 256) {
        const int t2 = tid >> 5;   // k-tile slot 0..7
        const int kc = tid & 31;
        float s = red[t2 * 32 + kc] + red[(t2 + 8) * 32 + kc];
        out[(size_t)b * KTOT + (kg * 8 + t2) * 32 + kc] = s;
    }
}

extern "C" void kernel_launch(void* const* d_in, const int* in_sizes, int n_in,
                              void* d_out, int out_size, void* d_ws, size_t ws_size,
                              hipStream_t stream) {
    const float* C   = (const float*)d_in[0];
    const float* dom = (const float*)d_in[1];
    float* out       = (float*)d_out;
    const int B = in_sizes[0] / (NATOMS * 3);  // 32
    dim3 grid(8, B);  // 8 k-groups x B, each block owns 256 k outputs
    theta_layer_kernel<<<grid, BLOCK, 0, stream>>>(C, dom, out);
}